// Round 3
// baseline (1552.018 us; speedup 1.0000x reference)
//
#include <hip/hip_runtime.h>
#include <stdint.h>

typedef _Float16 f16;
typedef _Float16 f16x8 __attribute__((ext_vector_type(8)));
typedef _Float16 f16x4 __attribute__((ext_vector_type(4)));
typedef float f32x4 __attribute__((ext_vector_type(4)));

__device__ __forceinline__ void gload_lds16(const void* g, void* l) {
    __builtin_amdgcn_global_load_lds(
        (const __attribute__((address_space(1))) unsigned int*)g,
        (__attribute__((address_space(3))) unsigned int*)l, 16, 0, 0);
}

#define VMWAIT(n) asm volatile("s_waitcnt vmcnt(" #n ")" ::: "memory")
#define LGKM0()   asm volatile("s_waitcnt lgkmcnt(0)" ::: "memory")

// ---------------------------------------------------------------------------
__global__ __launch_bounds__(256) void cvt_f32_f16(const float* __restrict__ s,
                                                   f16* __restrict__ d, int n8) {
    int i = blockIdx.x * 256 + threadIdx.x;
    if (i >= n8) return;
    const float4* s4 = (const float4*)s;
    float4 a = s4[2 * (size_t)i];
    float4 b = s4[2 * (size_t)i + 1];
    f16x8 o;
    o[0] = (f16)a.x; o[1] = (f16)a.y; o[2] = (f16)a.z; o[3] = (f16)a.w;
    o[4] = (f16)b.x; o[5] = (f16)b.y; o[6] = (f16)b.z; o[7] = (f16)b.w;
    *(f16x8*)(d + (size_t)i * 8) = o;
}

// ---------------------------------------------------------------------------
// 256x256 BT-GEMM, BK=32, 512 threads = 8 waves (2x4), 4-deep LDS ring,
// counted vmcnt(8), inline-asm ds_read_b128 (rule #18), per-tile 2-phase
// interleave, T2 swizzle, T5 setprio, T1 bijective XCD swizzle.
template <typename OutT>
__global__ __launch_bounds__(512, 2) void gemm256(
    const f16* __restrict__ A, const f16* __restrict__ B, OutT* __restrict__ C,
    int ldA, int ldB, long long ldC, int K, float alpha,
    long long sAh, long long sAb, long long sBh, long long sBb,
    long long sCh, long long sCb, int NB, int gx, int gy) {
    extern __shared__ char lds[];

    const int nwg = gridDim.x;
    const int q = nwg >> 3, r = nwg & 7;
    const int xcd = blockIdx.x & 7, lid = blockIdx.x >> 3;
    const int wg = (xcd < r ? xcd * (q + 1) : r * (q + 1) + (xcd - r) * q) + lid;
    const int z = wg / (gx * gy);
    const int rem = wg - z * (gx * gy);
    const int by = rem / gx, bx = rem - by * gx;
    const int h = z / NB, bb = z - h * NB;
    A += h * sAh + bb * sAb;
    B += h * sBh + bb * sBb;
    C += h * sCh + bb * sCb;
    const int row0 = by * 256, col0 = bx * 256;

    const int tid  = threadIdx.x;
    const int lane = tid & 63;
    const int wid  = tid >> 6;
    const int wm   = wid >> 2;
    const int wn   = wid & 3;
    const int fr   = lane & 15;
    const int fkb  = (lane >> 4) << 4;
    const int swz  = fkb ^ (((fr >> 1) & 3) << 4);  // lane-constant swizzle term

    // LDS byte offsets (low 32 bits of generic LDS pointer = ds offset)
    const unsigned ldsbase = (unsigned)(uintptr_t)(char*)lds;
    const unsigned aBase = ldsbase + (unsigned)((wm * 128 + fr) * 64 + swz);
    const unsigned bBase = ldsbase + 65536u + (unsigned)((wn * 64 + fr) * 64 + swz);

    // staging: linear LDS dest, inverse-swizzled global source
    const int srow  = tid >> 2;
    const int sbyte = (tid & 3) << 4;
    const int scol  = (sbyte ^ (((srow >> 1) & 3) << 4)) >> 1;
    const f16* gA0 = A + (size_t)(row0 + srow) * ldA + scol;
    const f16* gA1 = A + (size_t)(row0 + 128 + srow) * ldA + scol;
    const f16* gB0 = B + (size_t)(col0 + srow) * ldB + scol;
    const f16* gB1 = B + (size_t)(col0 + 128 + srow) * ldB + scol;
    char* lA0 = (char*)lds + tid * 16;
    char* lB0 = lA0 + 65536;

    const int nkt = K >> 5;

#define STAGE_A(tt) do { int _bo = ((tt) & 3) << 14; size_t _ko = (size_t)(tt) * 32; \
        gload_lds16(gA0 + _ko, lA0 + _bo); gload_lds16(gA1 + _ko, lA0 + _bo + 8192); } while (0)
#define STAGE_B(tt) do { int _bo = ((tt) & 3) << 14; size_t _ko = (size_t)(tt) * 32; \
        gload_lds16(gB0 + _ko, lB0 + _bo); gload_lds16(gB1 + _ko, lB0 + _bo + 8192); } while (0)

    STAGE_A(0); STAGE_B(0); STAGE_A(1); STAGE_B(1); STAGE_A(2); STAGE_B(2);

    f32x4 acc[8][4] = {};
#define MF(i, j, av, bv) \
    acc[i][j] = __builtin_amdgcn_mfma_f32_16x16x32_f16(av, bv, acc[i][j], 0, 0, 0)

    for (int t = 0; t < nkt; ++t) {
        // counted wait: tile t resident (keep 2 future tiles = 8 loads in flight)
        if (t < nkt - 2)       VMWAIT(8);
        else if (t == nkt - 2) VMWAIT(4);
        else                   VMWAIT(0);
        __builtin_amdgcn_s_barrier();   // all waves' tile-t stages landed

        const unsigned bo = (unsigned)((t & 3) << 14);
        const unsigned aA = aBase + bo, aB = bBase + bo;

        // ---- phase 1: A-frags 0-3 + all B-frags; stage A-half of t+3
        f16x8 a0, a1, a2, a3, a4, a5, a6, a7, b0, b1, b2, b3;
        asm volatile("ds_read_b128 %0, %2 offset:0\n\t"
                     "ds_read_b128 %1, %2 offset:1024"
                     : "=&v"(a0), "=&v"(a1) : "v"(aA));
        asm volatile("ds_read_b128 %0, %2 offset:2048\n\t"
                     "ds_read_b128 %1, %2 offset:3072"
                     : "=&v"(a2), "=&v"(a3) : "v"(aA));
        asm volatile("ds_read_b128 %0, %2 offset:0\n\t"
                     "ds_read_b128 %1, %2 offset:1024"
                     : "=&v"(b0), "=&v"(b1) : "v"(aB));
        asm volatile("ds_read_b128 %0, %2 offset:2048\n\t"
                     "ds_read_b128 %1, %2 offset:3072"
                     : "=&v"(b2), "=&v"(b3) : "v"(aB));
        if (t + 3 < nkt) STAGE_A(t + 3);
        __builtin_amdgcn_s_barrier();
        LGKM0();
        __builtin_amdgcn_sched_barrier(0);  // rule #18: pin MFMA after the wait
        __builtin_amdgcn_s_setprio(1);
        MF(0,0,a0,b0); MF(0,1,a0,b1); MF(0,2,a0,b2); MF(0,3,a0,b3);
        MF(1,0,a1,b0); MF(1,1,a1,b1); MF(1,2,a1,b2); MF(1,3,a1,b3);
        MF(2,0,a2,b0); MF(2,1,a2,b1); MF(2,2,a2,b2); MF(2,3,a2,b3);
        MF(3,0,a3,b0); MF(3,1,a3,b1); MF(3,2,a3,b2); MF(3,3,a3,b3);
        __builtin_amdgcn_s_setprio(0);
        __builtin_amdgcn_s_barrier();

        // ---- phase 2: A-frags 4-7 (B reused); stage B-half of t+3
        asm volatile("ds_read_b128 %0, %2 offset:4096\n\t"
                     "ds_read_b128 %1, %2 offset:5120"
                     : "=&v"(a4), "=&v"(a5) : "v"(aA));
        asm volatile("ds_read_b128 %0, %2 offset:6144\n\t"
                     "ds_read_b128 %1, %2 offset:7168"
                     : "=&v"(a6), "=&v"(a7) : "v"(aA));
        if (t + 3 < nkt) STAGE_B(t + 3);
        __builtin_amdgcn_s_barrier();
        LGKM0();
        __builtin_amdgcn_sched_barrier(0);
        __builtin_amdgcn_s_setprio(1);
        MF(4,0,a4,b0); MF(4,1,a4,b1); MF(4,2,a4,b2); MF(4,3,a4,b3);
        MF(5,0,a5,b0); MF(5,1,a5,b1); MF(5,2,a5,b2); MF(5,3,a5,b3);
        MF(6,0,a6,b0); MF(6,1,a6,b1); MF(6,2,a6,b2); MF(6,3,a6,b3);
        MF(7,0,a7,b0); MF(7,1,a7,b1); MF(7,2,a7,b2); MF(7,3,a7,b3);
        __builtin_amdgcn_s_setprio(0);
        // phase-2 closing barrier = next iteration's top barrier
    }
#undef MF
#undef STAGE_A
#undef STAGE_B

    const int er = (lane >> 4) * 4;
#pragma unroll
    for (int i = 0; i < 8; ++i)
#pragma unroll
        for (int j = 0; j < 4; ++j)
#pragma unroll
            for (int rr = 0; rr < 4; ++rr) {
                size_t idx = (size_t)(row0 + wm * 128 + i * 16 + er + rr) * (size_t)ldC +
                             (size_t)(col0 + wn * 64 + j * 16 + fr);
                C[idx] = (OutT)(acc[i][j][rr] * alpha);
            }
}

// ---------------------------------------------------------------------------
__global__ __launch_bounds__(256) void reduce_split4(const float* __restrict__ p,
                                                     float* __restrict__ o, int n4) {
    int i = blockIdx.x * 256 + threadIdx.x;
    if (i >= n4) return;
    const float4* p4 = (const float4*)p;
    float4 a = p4[i], b = p4[i + 1048576], c = p4[i + 2097152], d = p4[i + 3145728];
    float4 s;
    s.x = a.x + b.x + c.x + d.x;
    s.y = a.y + b.y + c.y + d.y;
    s.z = a.z + b.z + c.z + d.z;
    s.w = a.w + b.w + c.w + d.w;
    ((float4*)o)[i] = s;
}

// ---------------------------------------------------------------------------
__global__ __launch_bounds__(256) void softmax_rows(f16* __restrict__ P) {
    const size_t row = blockIdx.x;
    f16* p = P + row * 1024;
    const int tid = threadIdx.x, lane = tid & 63, wid = tid >> 6;

    f16x4 v4 = *(const f16x4*)(p + tid * 4);
    float v[4];
#pragma unroll
    for (int t = 0; t < 4; ++t) {
        v[t] = (float)v4[t];
        if (v[t] == 0.0f) v[t] = -9e15f;
    }
    float m = fmaxf(fmaxf(v[0], v[1]), fmaxf(v[2], v[3]));
#pragma unroll
    for (int o = 32; o > 0; o >>= 1) m = fmaxf(m, __shfl_xor(m, o));
    __shared__ float red[8];
    if (lane == 0) red[wid] = m;
    __syncthreads();
    m = fmaxf(fmaxf(red[0], red[1]), fmaxf(red[2], red[3]));

    float e[4], s = 0.f;
#pragma unroll
    for (int t = 0; t < 4; ++t) { e[t] = __expf(v[t] - m); s += e[t]; }
#pragma unroll
    for (int o = 32; o > 0; o >>= 1) s += __shfl_xor(s, o);
    if (lane == 0) red[4 + wid] = s;
    __syncthreads();
    s = red[4] + red[5] + red[6] + red[7];
    float inv = 1.0f / s;

    f16x4 o4;
#pragma unroll
    for (int t = 0; t < 4; ++t) o4[t] = (f16)(e[t] * inv);
    *(f16x4*)(p + tid * 4) = o4;
}

// ---------------------------------------------------------------------------
extern "C" void kernel_launch(void* const* d_in, const int* in_sizes, int n_in,
                              void* d_out, int out_size, void* d_ws, size_t ws_size,
                              hipStream_t stream) {
    const float* q  = (const float*)d_in[0];
    const float* k  = (const float*)d_in[1];
    const float* v  = (const float*)d_in[2];
    const float* Wq = (const float*)d_in[3];
    const float* Wk = (const float*)d_in[4];
    const float* Wv = (const float*)d_in[5];
    const float* Wl = (const float*)d_in[6];
    float* out = (float*)d_out;

    (void)hipFuncSetAttribute((const void*)gemm256<f16>,
                              hipFuncAttributeMaxDynamicSharedMemorySize, 131072);
    (void)hipFuncSetAttribute((const void*)gemm256<float>,
                              hipFuncAttributeMaxDynamicSharedMemorySize, 131072);

    const size_t MB = 1024ull * 1024ull;
    char* ws = (char*)d_ws;
    f16* q_h  = (f16*)(ws + 0 * MB);
    f16* k_h  = (f16*)(ws + 8 * MB);
    f16* v_h  = (f16*)(ws + 16 * MB);
    f16* Wq_h = (f16*)(ws + 24 * MB);
    f16* Wk_h = (f16*)(ws + 40 * MB);
    f16* Wv_h = (f16*)(ws + 56 * MB);
    f16* Wl_h = (f16*)(ws + 72 * MB);

    cvt_f32_f16<<<2048, 256, 0, stream>>>(q, q_h, 524288);
    cvt_f32_f16<<<2048, 256, 0, stream>>>(k, k_h, 524288);
    cvt_f32_f16<<<2048, 256, 0, stream>>>(v, v_h, 524288);
    cvt_f32_f16<<<4096, 256, 0, stream>>>(Wq, Wq_h, 1048576);
    cvt_f32_f16<<<4096, 256, 0, stream>>>(Wk, Wk_h, 1048576);
    cvt_f32_f16<<<4096, 256, 0, stream>>>(Wv, Wv_h, 1048576);
    cvt_f32_f16<<<4096, 256, 0, stream>>>(Wl, Wl_h, 1048576);

    const long long M1 = 1048576ll;
    const long long M4 = 4194304ll;
    const float SCALE = 0.03125f;
    const size_t SMEM = 131072;

    if (ws_size >= 344ull * MB) {
        f16* in_q  = (f16*)(ws + 88 * MB);
        f16* in_k  = (f16*)(ws + 152 * MB);
        f16* in_vT = (f16*)(ws + 216 * MB);
        f16* P     = (f16*)(ws + 280 * MB);
        f16* h_cat = (f16*)(ws + 88 * MB);      // aliases in_q (dead after logits)
        float* part = (float*)(ws + 280 * MB);  // aliases P (dead after PV)

        gemm256<f16><<<512, 512, SMEM, stream>>>(
            q_h, Wq_h, in_q, 1024, 1024, 1024, 1024, 1.0f,
            0, 0, M1, 0, M4, 0, 1, 4, 16);
        gemm256<f16><<<512, 512, SMEM, stream>>>(
            k_h, Wk_h, in_k, 1024, 1024, 1024, 1024, 1.0f,
            0, 0, M1, 0, M4, 0, 1, 4, 16);
        gemm256<f16><<<512, 512, SMEM, stream>>>(
            Wv_h, v_h, in_vT, 1024, 1024, 1024, 1024, 1.0f,
            M1, 0, 0, M1, M4, M1, 4, 4, 4);
        gemm256<f16><<<512, 512, SMEM, stream>>>(
            in_q, in_k, P, 1024, 1024, 1024, 1024, SCALE,
            M4, M1, M4, M1, M4, M1, 4, 4, 4);
        softmax_rows<<<32768, 256, 0, stream>>>(P);
        gemm256<f16><<<512, 512, SMEM, stream>>>(
            P, in_vT, h_cat, 1024, 1024, 8192, 1024, 1.0f,
            M4, M1, M4, M1, 1024ll, 8388608ll, 4, 4, 4);
        gemm256<float><<<256, 512, SMEM, stream>>>(
            h_cat, Wl_h, part, 8192, 8192, 1024, 2048, 1.0f,
            0, 2048, 0, 2048, 0, 4194304ll, 4, 4, 16);
        reduce_split4<<<4096, 256, 0, stream>>>(part, out, 1048576);
    } else {
        f16* in_q  = (f16*)(ws + 88 * MB);
        f16* in_k  = (f16*)(ws + 96 * MB);
        f16* in_vT = (f16*)(ws + 104 * MB);
        f16* P     = (f16*)(ws + 112 * MB);
        f16* h_cat = (f16*)(ws + 120 * MB);
        for (int h = 0; h < 8; ++h) {
            gemm256<f16><<<64, 512, SMEM, stream>>>(
                q_h, Wq_h + h * M1, in_q, 1024, 1024, 1024, 1024, 1.0f,
                0, 0, 0, 0, 0, 0, 1, 4, 16);
            gemm256<f16><<<64, 512, SMEM, stream>>>(
                k_h, Wk_h + h * M1, in_k, 1024, 1024, 1024, 1024, 1.0f,
                0, 0, 0, 0, 0, 0, 1, 4, 16);
            gemm256<f16><<<64, 512, SMEM, stream>>>(
                Wv_h + h * M1, v_h, in_vT, 1024, 1024, 1024, 1024, 1.0f,
                0, 0, 0, M1, 0, M1, 4, 4, 4);
            gemm256<f16><<<64, 512, SMEM, stream>>>(
                in_q, in_k, P, 1024, 1024, 1024, 1024, SCALE,
                0, M1, 0, M1, 0, M1, 4, 4, 4);
            softmax_rows<<<4096, 256, 0, stream>>>(P);
            gemm256<f16><<<64, 512, SMEM, stream>>>(
                P, in_vT, h_cat + h * 1024, 1024, 1024, 8192, 1024, 1.0f,
                0, M1, 0, M1, 0, 8388608ll, 4, 4, 4);
        }
        gemm256<float><<<64, 512, SMEM, stream>>>(
            h_cat, Wl_h, out, 8192, 8192, 1024, 8192, 1.0f,
            0, 0, 0, 0, 0, 0, 1, 4, 16);
    }
}

// Round 4
// 1415.649 us; speedup vs baseline: 1.0963x; 1.0963x over previous
//
#include <hip/hip_runtime.h>
#include <stdint.h>

typedef _Float16 f16;
typedef _Float16 f16x8 __attribute__((ext_vector_type(8)));
typedef _Float16 f16x4 __attribute__((ext_vector_type(4)));
typedef float f32x4 __attribute__((ext_vector_type(4)));

__device__ __forceinline__ void gload_lds16(const void* g, void* l) {
    __builtin_amdgcn_global_load_lds(
        (const __attribute__((address_space(1))) unsigned int*)g,
        (__attribute__((address_space(3))) unsigned int*)l, 16, 0, 0);
}

#define VMWAIT0() asm volatile("s_waitcnt vmcnt(0)" ::: "memory")
#define LGKM0()   asm volatile("s_waitcnt lgkmcnt(0)" ::: "memory")

// ---------------------------------------------------------------------------
// fused f32->f16 conversion for all 7 inputs in ONE launch
struct Cvt7 {
    const float* s[7];
    f16* d[7];
    int n8[7];
};
__global__ __launch_bounds__(256) void cvt_f32_f16_multi(Cvt7 c) {
    const int seg = blockIdx.y;
    const int i = blockIdx.x * 256 + threadIdx.x;
    if (i >= c.n8[seg]) return;
    const float4* s4 = (const float4*)c.s[seg];
    float4 a = s4[2 * (size_t)i];
    float4 b = s4[2 * (size_t)i + 1];
    f16x8 o;
    o[0] = (f16)a.x; o[1] = (f16)a.y; o[2] = (f16)a.z; o[3] = (f16)a.w;
    o[4] = (f16)b.x; o[5] = (f16)b.y; o[6] = (f16)b.z; o[7] = (f16)b.w;
    *(f16x8*)(c.d[seg] + (size_t)i * 8) = o;
}

// ---------------------------------------------------------------------------
// 256x256 BT-GEMM, BK=64, 512 threads = 8 waves (2Mx4N), double-buffered LDS
// (128 KiB), T3-minimum 2-phase schedule (verified m230/m248 recipe):
//   loop: STAGE(next) -> ds_read cur (2 k-halves, each lgkm0+32 MFMA)
//         -> vmcnt(0) -> barrier -> swap.
// T2 swizzle: byte ^= ((row&7)<<4) on 128-B rows; staging keeps LDS linear
// and inverse-swizzles the GLOBAL source (both-sides rule).
// C[m,n] = alpha * sum_k A[m,k]*B[n,k]; batch z -> (h=z/NB, b=z%NB).
template <typename OutT>
__global__ __launch_bounds__(512, 2) void gemm2ph(
    const f16* __restrict__ A, const f16* __restrict__ B, OutT* __restrict__ C,
    int ldA, int ldB, long long ldC, int K, float alpha,
    long long sAh, long long sAb, long long sBh, long long sBb,
    long long sCh, long long sCb, int NB, int gx, int gy) {
    extern __shared__ char lds[];
    // layout: [A0 32K][B0 32K][A1 32K][B1 32K]

    // T1 bijective XCD swizzle
    const int nwg = gridDim.x;
    const int q = nwg >> 3, r = nwg & 7;
    const int xcd = blockIdx.x & 7, lid = blockIdx.x >> 3;
    const int wg = (xcd < r ? xcd * (q + 1) : r * (q + 1) + (xcd - r) * q) + lid;
    const int z = wg / (gx * gy);
    const int rem = wg - z * (gx * gy);
    const int by = rem / gx, bx = rem - by * gx;
    const int h = z / NB, bb = z - h * NB;
    A += h * sAh + bb * sAb;
    B += h * sBh + bb * sBb;
    C += h * sCh + bb * sCb;
    const int row0 = by * 256, col0 = bx * 256;

    const int tid  = threadIdx.x;
    const int lane = tid & 63;
    const int wid  = tid >> 6;
    const int wm   = wid >> 2;          // 0..1 -> rows wm*128
    const int wn   = wid & 3;           // 0..3 -> cols wn*64
    const int fr   = lane & 15;
    const int fkb  = (lane >> 4) << 4;  // k byte offset within 32-col half
    const int sw0  = fkb ^ ((fr & 7) << 4);        // ks=0 swizzled col bytes
    const int sw1  = sw0 ^ 64;                     // ks=1 (flip bit 6)

    const unsigned ldsbase = (unsigned)(uintptr_t)(char*)lds;
    const unsigned aRow = ldsbase + (unsigned)((wm * 128 + fr) * 128);
    const unsigned bRow = ldsbase + 32768u + (unsigned)((wn * 64 + fr) * 128);

    // staging: thread -> A row (tid>>3) + it*64, 16B slot (tid&7), inverse-swz
    const int srow  = tid >> 3;
    const int scol  = (((tid & 7) ^ ((tid >> 3) & 7)) << 4) >> 1;  // element col
    const f16* gA = A + (size_t)(row0 + srow) * ldA + scol;
    const f16* gB = B + (size_t)(col0 + srow) * ldB + scol;
    char* lA = (char*)lds + tid * 16;
    char* lB = lA + 32768;

    const int nkt = K >> 6;

#define STAGE(tt, bufo) do { \
        const size_t _ko = (size_t)(tt) * 64; \
        gload_lds16(gA + _ko,                        lA + (bufo)); \
        gload_lds16(gA + 64  * (size_t)ldA + _ko,    lA + (bufo) + 8192); \
        gload_lds16(gA + 128 * (size_t)ldA + _ko,    lA + (bufo) + 16384); \
        gload_lds16(gA + 192 * (size_t)ldA + _ko,    lA + (bufo) + 24576); \
        gload_lds16(gB + _ko,                        lB + (bufo)); \
        gload_lds16(gB + 64  * (size_t)ldB + _ko,    lB + (bufo) + 8192); \
        gload_lds16(gB + 128 * (size_t)ldB + _ko,    lB + (bufo) + 16384); \
        gload_lds16(gB + 192 * (size_t)ldB + _ko,    lB + (bufo) + 24576); \
    } while (0)

#define DSR2(r0, r1, addr, o0, o1) \
    asm volatile("ds_read_b128 %0, %2 offset:" #o0 "\n\t" \
                 "ds_read_b128 %1, %2 offset:" #o1 \
                 : "=&v"(r0), "=&v"(r1) : "v"(addr))

#define MF(i, j, av, bv) \
    acc[i][j] = __builtin_amdgcn_mfma_f32_16x16x32_f16(av, bv, acc[i][j], 0, 0, 0)

#define HALF(sw) do { \
        f16x8 a0, a1, a2, a3, a4, a5, a6, a7, b0, b1, b2, b3; \
        const unsigned aA = aRow + bo + (sw); \
        const unsigned aB = bRow + bo + (sw); \
        DSR2(a0, a1, aA, 0, 2048); \
        DSR2(a2, a3, aA, 4096, 6144); \
        DSR2(a4, a5, aA, 8192, 10240); \
        DSR2(a6, a7, aA, 12288, 14336); \
        DSR2(b0, b1, aB, 0, 2048); \
        DSR2(b2, b3, aB, 4096, 6144); \
        LGKM0(); \
        __builtin_amdgcn_sched_barrier(0); \
        __builtin_amdgcn_s_setprio(1); \
        MF(0,0,a0,b0); MF(0,1,a0,b1); MF(0,2,a0,b2); MF(0,3,a0,b3); \
        MF(1,0,a1,b0); MF(1,1,a1,b1); MF(1,2,a1,b2); MF(1,3,a1,b3); \
        MF(2,0,a2,b0); MF(2,1,a2,b1); MF(2,2,a2,b2); MF(2,3,a2,b3); \
        MF(3,0,a3,b0); MF(3,1,a3,b1); MF(3,2,a3,b2); MF(3,3,a3,b3); \
        MF(4,0,a4,b0); MF(4,1,a4,b1); MF(4,2,a4,b2); MF(4,3,a4,b3); \
        MF(5,0,a5,b0); MF(5,1,a5,b1); MF(5,2,a5,b2); MF(5,3,a5,b3); \
        MF(6,0,a6,b0); MF(6,1,a6,b1); MF(6,2,a6,b2); MF(6,3,a6,b3); \
        MF(7,0,a7,b0); MF(7,1,a7,b1); MF(7,2,a7,b2); MF(7,3,a7,b3); \
        __builtin_amdgcn_s_setprio(0); \
    } while (0)

    // prologue: stage tile 0, drain, join
    STAGE(0, 0);
    VMWAIT0();
    __builtin_amdgcn_s_barrier();

    f32x4 acc[8][4] = {};
    unsigned cur = 0;

    for (int t = 0; t < nkt; ++t) {
        const unsigned bo = cur << 16;
        if (t + 1 < nkt) STAGE(t + 1, bo ^ 65536u);  // issue BEFORE compute
        HALF(sw0);
        HALF(sw1);
        VMWAIT0();                       // next tile landed (covered by MFMAs)
        __builtin_amdgcn_s_barrier();    // all waves done reading cur
        cur ^= 1;
    }
#undef HALF
#undef MF
#undef DSR2
#undef STAGE

    // C/D layout: col = lane&15, row = (lane>>4)*4 + reg
    const int er = (lane >> 4) * 4;
#pragma unroll
    for (int i = 0; i < 8; ++i)
#pragma unroll
        for (int j = 0; j < 4; ++j)
#pragma unroll
            for (int rr = 0; rr < 4; ++rr) {
                size_t idx = (size_t)(row0 + wm * 128 + i * 16 + er + rr) * (size_t)ldC +
                             (size_t)(col0 + wn * 64 + j * 16 + fr);
                C[idx] = (OutT)(acc[i][j][rr] * alpha);
            }
}

// ---------------------------------------------------------------------------
__global__ __launch_bounds__(256) void reduce_split4(const float* __restrict__ p,
                                                     float* __restrict__ o, int n4) {
    int i = blockIdx.x * 256 + threadIdx.x;
    if (i >= n4) return;
    const float4* p4 = (const float4*)p;
    float4 a = p4[i], b = p4[i + 1048576], c = p4[i + 2097152], d = p4[i + 3145728];
    float4 s;
    s.x = a.x + b.x + c.x + d.x;
    s.y = a.y + b.y + c.y + d.y;
    s.z = a.z + b.z + c.z + d.z;
    s.w = a.w + b.w + c.w + d.w;
    ((float4*)o)[i] = s;
}

// ---------------------------------------------------------------------------
__global__ __launch_bounds__(256) void softmax_rows(f16* __restrict__ P) {
    const size_t row = blockIdx.x;
    f16* p = P + row * 1024;
    const int tid = threadIdx.x, lane = tid & 63, wid = tid >> 6;

    f16x4 v4 = *(const f16x4*)(p + tid * 4);
    float v[4];
#pragma unroll
    for (int t = 0; t < 4; ++t) {
        v[t] = (float)v4[t];
        if (v[t] == 0.0f) v[t] = -9e15f;
    }
    float m = fmaxf(fmaxf(v[0], v[1]), fmaxf(v[2], v[3]));
#pragma unroll
    for (int o = 32; o > 0; o >>= 1) m = fmaxf(m, __shfl_xor(m, o));
    __shared__ float red[8];
    if (lane == 0) red[wid] = m;
    __syncthreads();
    m = fmaxf(fmaxf(red[0], red[1]), fmaxf(red[2], red[3]));

    float e[4], s = 0.f;
#pragma unroll
    for (int t = 0; t < 4; ++t) { e[t] = __expf(v[t] - m); s += e[t]; }
#pragma unroll
    for (int o = 32; o > 0; o >>= 1) s += __shfl_xor(s, o);
    if (lane == 0) red[4 + wid] = s;
    __syncthreads();
    s = red[4] + red[5] + red[6] + red[7];
    float inv = 1.0f / s;

    f16x4 o4;
#pragma unroll
    for (int t = 0; t < 4; ++t) o4[t] = (f16)(e[t] * inv);
    *(f16x4*)(p + tid * 4) = o4;
}

// ---------------------------------------------------------------------------
extern "C" void kernel_launch(void* const* d_in, const int* in_sizes, int n_in,
                              void* d_out, int out_size, void* d_ws, size_t ws_size,
                              hipStream_t stream) {
    const float* q  = (const float*)d_in[0];
    const float* k  = (const float*)d_in[1];
    const float* v  = (const float*)d_in[2];
    const float* Wq = (const float*)d_in[3];
    const float* Wk = (const float*)d_in[4];
    const float* Wv = (const float*)d_in[5];
    const float* Wl = (const float*)d_in[6];
    float* out = (float*)d_out;

    (void)hipFuncSetAttribute((const void*)gemm2ph<f16>,
                              hipFuncAttributeMaxDynamicSharedMemorySize, 131072);
    (void)hipFuncSetAttribute((const void*)gemm2ph<float>,
                              hipFuncAttributeMaxDynamicSharedMemorySize, 131072);

    const size_t MB = 1024ull * 1024ull;
    char* ws = (char*)d_ws;
    f16* q_h  = (f16*)(ws + 0 * MB);
    f16* k_h  = (f16*)(ws + 8 * MB);
    f16* v_h  = (f16*)(ws + 16 * MB);
    f16* Wq_h = (f16*)(ws + 24 * MB);
    f16* Wk_h = (f16*)(ws + 40 * MB);
    f16* Wv_h = (f16*)(ws + 56 * MB);
    f16* Wl_h = (f16*)(ws + 72 * MB);

    Cvt7 c;
    c.s[0] = q;  c.d[0] = q_h;  c.n8[0] = 524288;
    c.s[1] = k;  c.d[1] = k_h;  c.n8[1] = 524288;
    c.s[2] = v;  c.d[2] = v_h;  c.n8[2] = 524288;
    c.s[3] = Wq; c.d[3] = Wq_h; c.n8[3] = 1048576;
    c.s[4] = Wk; c.d[4] = Wk_h; c.n8[4] = 1048576;
    c.s[5] = Wv; c.d[5] = Wv_h; c.n8[5] = 1048576;
    c.s[6] = Wl; c.d[6] = Wl_h; c.n8[6] = 1048576;
    cvt_f32_f16_multi<<<dim3(4096, 7), 256, 0, stream>>>(c);

    const long long M1 = 1048576ll;   // S*D
    const long long M4 = 4194304ll;   // B*S*D
    const float SCALE = 0.03125f;     // 1/sqrt(1024)
    const size_t SMEM = 131072;

    if (ws_size >= 344ull * MB) {
        f16* in_q  = (f16*)(ws + 88 * MB);
        f16* in_k  = (f16*)(ws + 152 * MB);
        f16* in_vT = (f16*)(ws + 216 * MB);
        f16* P     = (f16*)(ws + 280 * MB);
        f16* h_cat = (f16*)(ws + 88 * MB);      // aliases in_q (dead after logits)
        float* part = (float*)(ws + 280 * MB);  // aliases P (dead after PV)

        gemm2ph<f16><<<512, 512, SMEM, stream>>>(
            q_h, Wq_h, in_q, 1024, 1024, 1024, 1024, 1.0f,
            0, 0, M1, 0, M4, 0, 1, 4, 16);
        gemm2ph<f16><<<512, 512, SMEM, stream>>>(
            k_h, Wk_h, in_k, 1024, 1024, 1024, 1024, 1.0f,
            0, 0, M1, 0, M4, 0, 1, 4, 16);
        gemm2ph<f16><<<512, 512, SMEM, stream>>>(
            Wv_h, v_h, in_vT, 1024, 1024, 1024, 1024, 1.0f,
            M1, 0, 0, M1, M4, M1, 4, 4, 4);
        gemm2ph<f16><<<512, 512, SMEM, stream>>>(
            in_q, in_k, P, 1024, 1024, 1024, 1024, SCALE,
            M4, M1, M4, M1, M4, M1, 4, 4, 4);
        softmax_rows<<<32768, 256, 0, stream>>>(P);
        gemm2ph<f16><<<512, 512, SMEM, stream>>>(
            P, in_vT, h_cat, 1024, 1024, 8192, 1024, 1.0f,
            M4, M1, M4, M1, 1024ll, 8388608ll, 4, 4, 4);
        // last dense: split-K=4 (K=2048 each) -> f32 partials -> reduce
        gemm2ph<float><<<256, 512, SMEM, stream>>>(
            h_cat, Wl_h, part, 8192, 8192, 1024, 2048, 1.0f,
            0, 2048, 0, 2048, 0, 4194304ll, 4, 4, 16);
        reduce_split4<<<4096, 256, 0, stream>>>(part, out, 1048576);
    } else {
        // chunked-by-head fallback (needs 184MB)
        f16* in_q  = (f16*)(ws + 88 * MB);
        f16* in_k  = (f16*)(ws + 96 * MB);
        f16* in_vT = (f16*)(ws + 104 * MB);
        f16* P     = (f16*)(ws + 112 * MB);
        f16* h_cat = (f16*)(ws + 120 * MB);
        for (int h = 0; h < 8; ++h) {
            gemm2ph<f16><<<64, 512, SMEM, stream>>>(
                q_h, Wq_h + h * M1, in_q, 1024, 1024, 1024, 1024, 1.0f,
                0, 0, 0, 0, 0, 0, 1, 4, 16);
            gemm2ph<f16><<<64, 512, SMEM, stream>>>(
                k_h, Wk_h + h * M1, in_k, 1024, 1024, 1024, 1024, 1.0f,
                0, 0, 0, 0, 0, 0, 1, 4, 16);
            gemm2ph<f16><<<64, 512, SMEM, stream>>>(
                Wv_h + h * M1, v_h, in_vT, 1024, 1024, 1024, 1024, 1.0f,
                0, 0, 0, M1, 0, M1, 4, 4, 4);
            gemm2ph<f16><<<64, 512, SMEM, stream>>>(
                in_q, in_k, P, 1024, 1024, 1024, 1024, SCALE,
                0, M1, 0, M1, 0, M1, 4, 4, 4);
            softmax_rows<<<4096, 256, 0, stream>>>(P);
            gemm2ph<f16><<<64, 512, SMEM, stream>>>(
                P, in_vT, h_cat + h * 1024, 1024, 1024, 8192, 1024, 1.0f,
                0, M1, 0, M1, 0, 8388608ll, 4, 4, 4);
        }
        gemm2ph<float><<<64, 512, SMEM, stream>>>(
            h_cat, Wl_h, out, 8192, 8192, 1024, 8192, 1.0f,
            0, 0, 0, 0, 0, 0, 1, 4, 16);
    }
}

// Round 6
// 471.456 us; speedup vs baseline: 3.2920x; 3.0027x over previous
//
#include <hip/hip_runtime.h>
#include <stdint.h>

typedef _Float16 f16;
typedef _Float16 f16x8 __attribute__((ext_vector_type(8)));
typedef _Float16 f16x4 __attribute__((ext_vector_type(4)));
typedef float f32x4 __attribute__((ext_vector_type(4)));

// ---------------------------------------------------------------------------
// async global->LDS, 16B per lane (R1-verified engine helper)
__device__ __forceinline__ void gload_lds16(const void* g, void* l) {
    __builtin_amdgcn_global_load_lds(
        (const __attribute__((address_space(1))) unsigned int*)g,
        (__attribute__((address_space(3))) unsigned int*)l, 16, 0, 0);
}

// ---------------------------------------------------------------------------
// fused f32->f16 conversion (plain), 4 segments: q, k, v, Wl
struct Cvt4 {
    const float* s[4];
    f16* d[4];
    int n8[4];
};
__global__ __launch_bounds__(256) void cvt_plain4(Cvt4 c) {
    const int seg = blockIdx.y;
    const int i = blockIdx.x * 256 + threadIdx.x;
    if (i >= c.n8[seg]) return;
    const float4* s4 = (const float4*)c.s[seg];
    float4 a = s4[2 * (size_t)i];
    float4 b = s4[2 * (size_t)i + 1];
    f16x8 o;
    o[0] = (f16)a.x; o[1] = (f16)a.y; o[2] = (f16)a.z; o[3] = (f16)a.w;
    o[4] = (f16)b.x; o[5] = (f16)b.y; o[6] = (f16)b.z; o[7] = (f16)b.w;
    *(f16x8*)(c.d[seg] + (size_t)i * 8) = o;
}

// ---------------------------------------------------------------------------
// transpose + cvt: src [h][1024(d)][1024(e)] f32 -> dst [h][1024(e)][1024(d)] f16
// 3 matrices (Wq, Wk, Wv). 64x64 tiles via LDS.
struct T3 { const float* s[3]; f16* d[3]; };
__global__ __launch_bounds__(256) void cvt_transpose3(T3 c) {
    const int bid = blockIdx.x;            // 16 dtiles x 16 etiles x 24 (m*8+h)
    const int dt = bid & 15;
    const int et = (bid >> 4) & 15;
    const int zz = bid >> 8;
    const int m = zz >> 3, h = zz & 7;
    const float* src = c.s[m] + (size_t)h * 1048576;
    f16* dst = c.d[m] + (size_t)h * 1048576;
    __shared__ f16 t[64][72];              // t[e-col][d-row], padded
    const int r  = threadIdx.x >> 2;       // 0..63
    const int cq = threadIdx.x & 3;        // 0..3
    const int d0 = dt * 64, e0 = et * 64;
#pragma unroll
    for (int i = 0; i < 4; ++i) {
        const int cc = cq * 4 + i * 16;
        float4 vv = *(const float4*)(src + (size_t)(d0 + r) * 1024 + e0 + cc);
        t[cc + 0][r] = (f16)vv.x;
        t[cc + 1][r] = (f16)vv.y;
        t[cc + 2][r] = (f16)vv.z;
        t[cc + 3][r] = (f16)vv.w;
    }
    __syncthreads();
#pragma unroll
    for (int i = 0; i < 4; ++i) {
        const int cc = cq * 4 + i * 16;
        f16x4 w;
        w[0] = t[r][cc + 0];
        w[1] = t[r][cc + 1];
        w[2] = t[r][cc + 2];
        w[3] = t[r][cc + 3];
        *(f16x4*)(dst + (size_t)(e0 + r) * 1024 + d0 + cc) = w;
    }
}

// ---------------------------------------------------------------------------
// R1-verified BT-GEMM: C[m,n] = alpha * sum_k A[m,k] * B[n,k]
// 128x128 tile, BK=64, 256 threads = 4 waves (2x2), 16x16x32 MFMA, XOR-swizzled
// LDS (linear LDS dest + inverse-swizzled global source). LDS 32KB -> up to
// 5 blocks/CU. Batch: z -> (h = z/NB, b = z%NB).
template <typename OutT>
__global__ __launch_bounds__(256, 2) void gemm_bt(
    const f16* __restrict__ A, const f16* __restrict__ B, OutT* __restrict__ C,
    int ldA, int ldB, long long ldC, int K, float alpha,
    long long sAh, long long sAb, long long sBh, long long sBb,
    long long sCh, long long sCb, int NB) {
    const int z = blockIdx.z;
    const int h = z / NB, bb = z % NB;
    A += h * sAh + bb * sAb;
    B += h * sBh + bb * sBb;
    C += h * sCh + bb * sCb;

    const int row0 = blockIdx.y * 128;
    const int col0 = blockIdx.x * 128;

    __shared__ __align__(16) f16 smA[128 * 64];
    __shared__ __align__(16) f16 smB[128 * 64];

    const int tid  = threadIdx.x;
    const int lane = tid & 63;
    const int wid  = tid >> 6;
    const int wr   = (wid >> 1) * 64;
    const int wc   = (wid & 1) * 64;
    const int fr   = lane & 15;
    const int fkb  = (lane >> 4) * 16;

    f32x4 acc[4][4] = {};

    const int nkt = K >> 6;
    for (int kt = 0; kt < nkt; ++kt) {
#pragma unroll
        for (int it = 0; it < 4; ++it) {
            int p = (it * 256 + tid) * 16;
            int n = p ^ (((p >> 7) & 7) << 4);
            int r   = n >> 7;
            int kel = (n & 127) >> 1;
            size_t ga = (size_t)(row0 + r) * (size_t)ldA + (size_t)(kt * 64 + kel);
            gload_lds16(A + ga, (char*)smA + p);
            size_t gb = (size_t)(col0 + r) * (size_t)ldB + (size_t)(kt * 64 + kel);
            gload_lds16(B + gb, (char*)smB + p);
        }
        __syncthreads();

#pragma unroll
        for (int ks = 0; ks < 2; ++ks) {
            f16x8 af[4], bf[4];
#pragma unroll
            for (int i = 0; i < 4; ++i) {
                int rowA = wr + i * 16 + fr;
                int na   = rowA * 128 + ks * 64 + fkb;
                af[i] = *(const f16x8*)((const char*)smA + (na ^ ((rowA & 7) << 4)));
                int rowB = wc + i * 16 + fr;
                int nb   = rowB * 128 + ks * 64 + fkb;
                bf[i] = *(const f16x8*)((const char*)smB + (nb ^ ((rowB & 7) << 4)));
            }
#pragma unroll
            for (int i = 0; i < 4; ++i)
#pragma unroll
                for (int j = 0; j < 4; ++j)
                    acc[i][j] = __builtin_amdgcn_mfma_f32_16x16x32_f16(
                        af[i], bf[j], acc[i][j], 0, 0, 0);
        }
        __syncthreads();
    }

    const int er = (lane >> 4) * 4;
#pragma unroll
    for (int i = 0; i < 4; ++i)
#pragma unroll
        for (int j = 0; j < 4; ++j)
#pragma unroll
            for (int r = 0; r < 4; ++r) {
                size_t idx = (size_t)(row0 + wr + i * 16 + er + r) * (size_t)ldC +
                             (size_t)(col0 + wc + j * 16 + fr);
                C[idx] = (OutT)(acc[i][j][r] * alpha);
            }
}

// ---------------------------------------------------------------------------
// reduce 2 split-K partials: part [b][ks][1024x1024] f32 -> out [b][1024x1024]
__global__ __launch_bounds__(256) void reduce_split2(const float* __restrict__ p,
                                                     float* __restrict__ o, int n4) {
    int i = blockIdx.x * 256 + threadIdx.x;
    if (i >= n4) return;                      // n4 = 1048576 float4s
    const int b  = i >> 18;                   // 262144 float4 per batch image
    const int jj = i & 262143;
    const float4* p4 = (const float4*)p;
    const size_t base = (size_t)b * 524288 + jj;
    float4 a = p4[base], c = p4[base + 262144];
    float4 s;
    s.x = a.x + c.x;
    s.y = a.y + c.y;
    s.z = a.z + c.z;
    s.w = a.w + c.w;
    ((float4*)o)[i] = s;
}

// ---------------------------------------------------------------------------
// Row softmax over 1024 f16 logits, in place; exact-zero -> -9e15 (faithful).
__global__ __launch_bounds__(256) void softmax_rows(f16* __restrict__ P) {
    const size_t row = blockIdx.x;
    f16* p = P + row * 1024;
    const int tid = threadIdx.x, lane = tid & 63, wid = tid >> 6;

    f16x4 v4 = *(const f16x4*)(p + tid * 4);
    float v[4];
#pragma unroll
    for (int t = 0; t < 4; ++t) {
        v[t] = (float)v4[t];
        if (v[t] == 0.0f) v[t] = -9e15f;
    }
    float m = fmaxf(fmaxf(v[0], v[1]), fmaxf(v[2], v[3]));
#pragma unroll
    for (int o = 32; o > 0; o >>= 1) m = fmaxf(m, __shfl_xor(m, o));
    __shared__ float red[8];
    if (lane == 0) red[wid] = m;
    __syncthreads();
    m = fmaxf(fmaxf(red[0], red[1]), fmaxf(red[2], red[3]));

    float e[4], s = 0.f;
#pragma unroll
    for (int t = 0; t < 4; ++t) { e[t] = __expf(v[t] - m); s += e[t]; }
#pragma unroll
    for (int o = 32; o > 0; o >>= 1) s += __shfl_xor(s, o);
    if (lane == 0) red[4 + wid] = s;
    __syncthreads();
    s = red[4] + red[5] + red[6] + red[7];
    float inv = 1.0f / s;

    f16x4 o4;
#pragma unroll
    for (int t = 0; t < 4; ++t) o4[t] = (f16)(e[t] * inv);
    *(f16x4*)(p + tid * 4) = o4;
}

// ---------------------------------------------------------------------------
// Algebra (per head h, batch b):
//   Mt_h[e',e]  = sum_d Wk[h,d,e'] Wq[h,d,e]            = BT(WkT_h, WqT_h)
//   Aq[h,b,s,e'] = sum_e q[b,s,e] Mt_h[e',e]            = BT(q_b, Mt_h)
//   P[b,s,h*S+t] = scale * sum_e' Aq[h,b,s,e'] k[b,t,e'] = BT(Aq_hb, k_b)
//   G_h[e,e']   = sum_d Wl[e,h*1024+d] Wv[h,d,e']       = BT(Wl(+h*1024), WvT_h)
//   Xt[b][e,h*S+t] = sum_e' G_h[e,e'] v[b,t,e']         = BT(G_h, v_b)
//   out[b][s,e] = sum_{h,t} P[b,s,h*S+t] Xt[b,e,h*S+t]  = BT(P_b, Xt_b), K=8192
// 309 GF total (vs 412 naive). Workspace plan peaks at EXACTLY 184 MiB
// (proven safe: R1's fallback used [0,184) and passed; ws_size >= 184 MiB,
// and < 344 MiB per the R5 crash).
extern "C" void kernel_launch(void* const* d_in, const int* in_sizes, int n_in,
                              void* d_out, int out_size, void* d_ws, size_t ws_size,
                              hipStream_t stream) {
    const float* q  = (const float*)d_in[0];
    const float* k  = (const float*)d_in[1];
    const float* v  = (const float*)d_in[2];
    const float* Wq = (const float*)d_in[3];
    const float* Wk = (const float*)d_in[4];
    const float* Wv = (const float*)d_in[5];
    const float* Wl = (const float*)d_in[6];
    float* out = (float*)d_out;

    const size_t MB = 1024ull * 1024ull;
    char* ws = (char*)d_ws;
    // phase-1 residents
    f16*  q_h  = (f16*)(ws + 0 * MB);     // 8 MiB  [B*S][E]
    f16*  k_h  = (f16*)(ws + 8 * MB);     // 8 MiB  (live until P)
    f16*  v_h  = (f16*)(ws + 16 * MB);    // 8 MiB  (live until Xt)
    f16*  Wl_h = (f16*)(ws + 24 * MB);    // 16 MiB [E][H*D]   (dead after G)
    f16*  WqT  = (f16*)(ws + 40 * MB);    // 16 MiB [h][e][d]  (dead after Mt)
    f16*  WkT  = (f16*)(ws + 56 * MB);    // 16 MiB            (dead after Mt)
    f16*  WvT  = (f16*)(ws + 72 * MB);    // 16 MiB            (dead after G)
    f16*  Mt   = (f16*)(ws + 88 * MB);    // 16 MiB [h][e'][e] (dead after Aq)
    f16*  G    = (f16*)(ws + 104 * MB);   // 16 MiB [h][e][e'] (dead after Xt)
    // phase-2 aliases
    f16*  Aq   = (f16*)(ws + 24 * MB);    // 64 MiB [h][b][s][e'] (over W buffers)
    f16*  P    = (f16*)(ws + 120 * MB);   // 64 MiB [b][s][h*1024+t]
    f16*  Xt   = (f16*)(ws + 24 * MB);    // 64 MiB [b][e][h*1024+t] (over Aq)
    float* part = (float*)(ws + 88 * MB); // 32 MiB [b][ks][s][e] (over Mt,G)

    // ---- conversions
    Cvt4 c4;
    c4.s[0] = q;  c4.d[0] = q_h;  c4.n8[0] = 524288;
    c4.s[1] = k;  c4.d[1] = k_h;  c4.n8[1] = 524288;
    c4.s[2] = v;  c4.d[2] = v_h;  c4.n8[2] = 524288;
    c4.s[3] = Wl; c4.d[3] = Wl_h; c4.n8[3] = 1048576;
    cvt_plain4<<<dim3(4096, 4), 256, 0, stream>>>(c4);

    T3 t3;
    t3.s[0] = Wq; t3.d[0] = WqT;
    t3.s[1] = Wk; t3.d[1] = WkT;
    t3.s[2] = Wv; t3.d[2] = WvT;
    cvt_transpose3<<<6144, 256, 0, stream>>>(t3);

    const long long M1 = 1048576ll;   // 1024*1024
    const long long M8 = 8388608ll;   // 1024*8192
    const float SCALE = 0.03125f;     // 1/sqrt(1024)
    dim3 blk(256);

    // ---- Mt_h = BT(WkT_h, WqT_h)   [8 batches, K=1024]
    gemm_bt<f16><<<dim3(8, 8, 8), blk, 0, stream>>>(
        WkT, WqT, Mt, 1024, 1024, 1024, 1024, 1.0f,
        M1, 0, M1, 0, M1, 0, 1);
    // ---- G_h = BT(Wl_h(+h*1024), WvT_h)
    gemm_bt<f16><<<dim3(8, 8, 8), blk, 0, stream>>>(
        Wl_h, WvT, G, 8192, 1024, 1024, 1024, 1.0f,
        1024, 0, M1, 0, M1, 0, 1);
    // ---- Aq[h][b] = BT(q_b, Mt_h)   z=(h,b), NB=4  (overwrites W buffers)
    gemm_bt<f16><<<dim3(8, 8, 32), blk, 0, stream>>>(
        q_h, Mt, Aq, 1024, 1024, 1024, 1024, 1.0f,
        0, M1, M1, 0, 4 * M1, M1, 4);
    // ---- P[b][s][h*1024+t] = SCALE * BT(Aq[h][b], k_b)
    gemm_bt<f16><<<dim3(8, 8, 32), blk, 0, stream>>>(
        Aq, k_h, P, 1024, 1024, 8192, 1024, SCALE,
        4 * M1, M1, 0, M1, 1024, M8, 4);
    // ---- Xt[b][e][h*1024+t] = BT(G_h, v_b)   (overwrites dead Aq)
    gemm_bt<f16><<<dim3(8, 8, 32), blk, 0, stream>>>(
        G, v_h, Xt, 1024, 1024, 8192, 1024, 1.0f,
        M1, 0, 0, M1, 1024, M8, 4);
    // ---- softmax over 32768 contiguous rows of 1024 = per-(b,s,h) slices
    softmax_rows<<<32768, 256, 0, stream>>>(P);
    // ---- out partials: split-K=2, z=(b,ks), NB=2, K=4096 each
    gemm_bt<float><<<dim3(8, 8, 8), blk, 0, stream>>>(
        P, Xt, part, 8192, 8192, 1024, 4096, 1.0f,
        M8, 4096, M8, 4096, 2 * M1, M1, 2);
    // ---- reduce split-K partials -> out
    reduce_split2<<<4096, 256, 0, stream>>>(part, out, 1048576);
}

// Round 7
// 435.287 us; speedup vs baseline: 3.5655x; 1.0831x over previous
//
#include <hip/hip_runtime.h>
#include <stdint.h>

typedef _Float16 f16;
typedef _Float16 f16x8 __attribute__((ext_vector_type(8)));
typedef _Float16 f16x4 __attribute__((ext_vector_type(4)));
typedef float f32x4 __attribute__((ext_vector_type(4)));

__device__ __forceinline__ void gload_lds16(const void* g, void* l) {
    __builtin_amdgcn_global_load_lds(
        (const __attribute__((address_space(1))) unsigned int*)g,
        (__attribute__((address_space(3))) unsigned int*)l, 16, 0, 0);
}

#define VMWAIT0() asm volatile("s_waitcnt vmcnt(0)" ::: "memory")
#define LGKM0()   asm volatile("s_waitcnt lgkmcnt(0)" ::: "memory")

// ---------------------------------------------------------------------------
// fused f32->f16 conversion (plain), 4 segments: q, k, v, Wl
struct Cvt4 {
    const float* s[4];
    f16* d[4];
    int n8[4];
};
__global__ __launch_bounds__(256) void cvt_plain4(Cvt4 c) {
    const int seg = blockIdx.y;
    const int i = blockIdx.x * 256 + threadIdx.x;
    if (i >= c.n8[seg]) return;
    const float4* s4 = (const float4*)c.s[seg];
    float4 a = s4[2 * (size_t)i];
    float4 b = s4[2 * (size_t)i + 1];
    f16x8 o;
    o[0] = (f16)a.x; o[1] = (f16)a.y; o[2] = (f16)a.z; o[3] = (f16)a.w;
    o[4] = (f16)b.x; o[5] = (f16)b.y; o[6] = (f16)b.z; o[7] = (f16)b.w;
    *(f16x8*)(c.d[seg] + (size_t)i * 8) = o;
}

// ---------------------------------------------------------------------------
// transpose + cvt: src [h][1024(d)][1024(e)] f32 -> dst [h][1024(e)][1024(d)] f16
struct T3 { const float* s[3]; f16* d[3]; };
__global__ __launch_bounds__(256) void cvt_transpose3(T3 c) {
    const int bid = blockIdx.x;
    const int dt = bid & 15;
    const int et = (bid >> 4) & 15;
    const int zz = bid >> 8;
    const int m = zz >> 3, h = zz & 7;
    const float* src = c.s[m] + (size_t)h * 1048576;
    f16* dst = c.d[m] + (size_t)h * 1048576;
    __shared__ f16 t[64][72];
    const int r  = threadIdx.x >> 2;
    const int cq = threadIdx.x & 3;
    const int d0 = dt * 64, e0 = et * 64;
#pragma unroll
    for (int i = 0; i < 4; ++i) {
        const int cc = cq * 4 + i * 16;
        float4 vv = *(const float4*)(src + (size_t)(d0 + r) * 1024 + e0 + cc);
        t[cc + 0][r] = (f16)vv.x;
        t[cc + 1][r] = (f16)vv.y;
        t[cc + 2][r] = (f16)vv.z;
        t[cc + 3][r] = (f16)vv.w;
    }
    __syncthreads();
#pragma unroll
    for (int i = 0; i < 4; ++i) {
        const int cc = cq * 4 + i * 16;
        f16x4 w;
        w[0] = t[r][cc + 0];
        w[1] = t[r][cc + 1];
        w[2] = t[r][cc + 2];
        w[3] = t[r][cc + 3];
        *(f16x4*)(dst + (size_t)(e0 + r) * 1024 + d0 + cc) = w;
    }
}

// ---------------------------------------------------------------------------
// R1-verified 128x128 BT-GEMM (kept for small/odd-grid shapes).
template <typename OutT>
__global__ __launch_bounds__(256, 2) void gemm_bt(
    const f16* __restrict__ A, const f16* __restrict__ B, OutT* __restrict__ C,
    int ldA, int ldB, long long ldC, int K, float alpha,
    long long sAh, long long sAb, long long sBh, long long sBb,
    long long sCh, long long sCb, int NB) {
    const int z = blockIdx.z;
    const int h = z / NB, bb = z % NB;
    A += h * sAh + bb * sAb;
    B += h * sBh + bb * sBb;
    C += h * sCh + bb * sCb;

    const int row0 = blockIdx.y * 128;
    const int col0 = blockIdx.x * 128;

    __shared__ __align__(16) f16 smA[128 * 64];
    __shared__ __align__(16) f16 smB[128 * 64];

    const int tid  = threadIdx.x;
    const int lane = tid & 63;
    const int wid  = tid >> 6;
    const int wr   = (wid >> 1) * 64;
    const int wc   = (wid & 1) * 64;
    const int fr   = lane & 15;
    const int fkb  = (lane >> 4) * 16;

    f32x4 acc[4][4] = {};

    const int nkt = K >> 6;
    for (int kt = 0; kt < nkt; ++kt) {
#pragma unroll
        for (int it = 0; it < 4; ++it) {
            int p = (it * 256 + tid) * 16;
            int n = p ^ (((p >> 7) & 7) << 4);
            int r   = n >> 7;
            int kel = (n & 127) >> 1;
            size_t ga = (size_t)(row0 + r) * (size_t)ldA + (size_t)(kt * 64 + kel);
            gload_lds16(A + ga, (char*)smA + p);
            size_t gb = (size_t)(col0 + r) * (size_t)ldB + (size_t)(kt * 64 + kel);
            gload_lds16(B + gb, (char*)smB + p);
        }
        __syncthreads();

#pragma unroll
        for (int ks = 0; ks < 2; ++ks) {
            f16x8 af[4], bf[4];
#pragma unroll
            for (int i = 0; i < 4; ++i) {
                int rowA = wr + i * 16 + fr;
                int na   = rowA * 128 + ks * 64 + fkb;
                af[i] = *(const f16x8*)((const char*)smA + (na ^ ((rowA & 7) << 4)));
                int rowB = wc + i * 16 + fr;
                int nb   = rowB * 128 + ks * 64 + fkb;
                bf[i] = *(const f16x8*)((const char*)smB + (nb ^ ((rowB & 7) << 4)));
            }
#pragma unroll
            for (int i = 0; i < 4; ++i)
#pragma unroll
                for (int j = 0; j < 4; ++j)
                    acc[i][j] = __builtin_amdgcn_mfma_f32_16x16x32_f16(
                        af[i], bf[j], acc[i][j], 0, 0, 0);
        }
        __syncthreads();
    }

    const int er = (lane >> 4) * 4;
#pragma unroll
    for (int i = 0; i < 4; ++i)
#pragma unroll
        for (int j = 0; j < 4; ++j)
#pragma unroll
            for (int r = 0; r < 4; ++r) {
                size_t idx = (size_t)(row0 + wr + i * 16 + er + r) * (size_t)ldC +
                             (size_t)(col0 + wc + j * 16 + fr);
                C[idx] = (OutT)(acc[i][j][r] * alpha);
            }
}

// ---------------------------------------------------------------------------
// R4-verified 256x256 BT-GEMM, BK=64, 8 waves, double-buffered LDS (128 KiB),
// 2-phase schedule, T2 swizzle, T5 setprio, T1 bijective XCD swizzle.
// 5.5 TF/CU measured (R4 fallback); here launched at 512 blocks (2 rounds/CU).
template <typename OutT>
__global__ __launch_bounds__(512, 2) void gemm2ph(
    const f16* __restrict__ A, const f16* __restrict__ B, OutT* __restrict__ C,
    int ldA, int ldB, long long ldC, int K, float alpha,
    long long sAh, long long sAb, long long sBh, long long sBb,
    long long sCh, long long sCb, int NB, int gx, int gy) {
    extern __shared__ char lds[];

    const int nwg = gridDim.x;
    const int q = nwg >> 3, r = nwg & 7;
    const int xcd = blockIdx.x & 7, lid = blockIdx.x >> 3;
    const int wg = (xcd < r ? xcd * (q + 1) : r * (q + 1) + (xcd - r) * q) + lid;
    const int z = wg / (gx * gy);
    const int rem = wg - z * (gx * gy);
    const int by = rem / gx, bx = rem - by * gx;
    const int h = z / NB, bb = z - h * NB;
    A += h * sAh + bb * sAb;
    B += h * sBh + bb * sBb;
    C += h * sCh + bb * sCb;
    const int row0 = by * 256, col0 = bx * 256;

    const int tid  = threadIdx.x;
    const int lane = tid & 63;
    const int wid  = tid >> 6;
    const int wm   = wid >> 2;
    const int wn   = wid & 3;
    const int fr   = lane & 15;
    const int fkb  = (lane >> 4) << 4;
    const int sw0  = fkb ^ ((fr & 7) << 4);
    const int sw1  = sw0 ^ 64;

    const unsigned ldsbase = (unsigned)(uintptr_t)(char*)lds;
    const unsigned aRow = ldsbase + (unsigned)((wm * 128 + fr) * 128);
    const unsigned bRow = ldsbase + 32768u + (unsigned)((wn * 64 + fr) * 128);

    const int srow  = tid >> 3;
    const int scol  = (((tid & 7) ^ ((tid >> 3) & 7)) << 4) >> 1;
    const f16* gA = A + (size_t)(row0 + srow) * ldA + scol;
    const f16* gB = B + (size_t)(col0 + srow) * ldB + scol;
    char* lA = (char*)lds + tid * 16;
    char* lB = lA + 32768;

    const int nkt = K >> 6;

#define STAGE(tt, bufo) do { \
        const size_t _ko = (size_t)(tt) * 64; \
        gload_lds16(gA + _ko,                        lA + (bufo)); \
        gload_lds16(gA + 64  * (size_t)ldA + _ko,    lA + (bufo) + 8192); \
        gload_lds16(gA + 128 * (size_t)ldA + _ko,    lA + (bufo) + 16384); \
        gload_lds16(gA + 192 * (size_t)ldA + _ko,    lA + (bufo) + 24576); \
        gload_lds16(gB + _ko,                        lB + (bufo)); \
        gload_lds16(gB + 64  * (size_t)ldB + _ko,    lB + (bufo) + 8192); \
        gload_lds16(gB + 128 * (size_t)ldB + _ko,    lB + (bufo) + 16384); \
        gload_lds16(gB + 192 * (size_t)ldB + _ko,    lB + (bufo) + 24576); \
    } while (0)

#define DSR2(r0, r1, addr, o0, o1) \
    asm volatile("ds_read_b128 %0, %2 offset:" #o0 "\n\t" \
                 "ds_read_b128 %1, %2 offset:" #o1 \
                 : "=&v"(r0), "=&v"(r1) : "v"(addr))

#define MF(i, j, av, bv) \
    acc[i][j] = __builtin_amdgcn_mfma_f32_16x16x32_f16(av, bv, acc[i][j], 0, 0, 0)

#define HALF(sw) do { \
        f16x8 a0, a1, a2, a3, a4, a5, a6, a7, b0, b1, b2, b3; \
        const unsigned aA = aRow + bo + (sw); \
        const unsigned aB = bRow + bo + (sw); \
        DSR2(a0, a1, aA, 0, 2048); \
        DSR2(a2, a3, aA, 4096, 6144); \
        DSR2(a4, a5, aA, 8192, 10240); \
        DSR2(a6, a7, aA, 12288, 14336); \
        DSR2(b0, b1, aB, 0, 2048); \
        DSR2(b2, b3, aB, 4096, 6144); \
        LGKM0(); \
        __builtin_amdgcn_sched_barrier(0); \
        __builtin_amdgcn_s_setprio(1); \
        MF(0,0,a0,b0); MF(0,1,a0,b1); MF(0,2,a0,b2); MF(0,3,a0,b3); \
        MF(1,0,a1,b0); MF(1,1,a1,b1); MF(1,2,a1,b2); MF(1,3,a1,b3); \
        MF(2,0,a2,b0); MF(2,1,a2,b1); MF(2,2,a2,b2); MF(2,3,a2,b3); \
        MF(3,0,a3,b0); MF(3,1,a3,b1); MF(3,2,a3,b2); MF(3,3,a3,b3); \
        MF(4,0,a4,b0); MF(4,1,a4,b1); MF(4,2,a4,b2); MF(4,3,a4,b3); \
        MF(5,0,a5,b0); MF(5,1,a5,b1); MF(5,2,a5,b2); MF(5,3,a5,b3); \
        MF(6,0,a6,b0); MF(6,1,a6,b1); MF(6,2,a6,b2); MF(6,3,a6,b3); \
        MF(7,0,a7,b0); MF(7,1,a7,b1); MF(7,2,a7,b2); MF(7,3,a7,b3); \
        __builtin_amdgcn_s_setprio(0); \
    } while (0)

    STAGE(0, 0);
    VMWAIT0();
    __builtin_amdgcn_s_barrier();

    f32x4 acc[8][4] = {};
    unsigned cur = 0;

    for (int t = 0; t < nkt; ++t) {
        const unsigned bo = cur << 16;
        if (t + 1 < nkt) STAGE(t + 1, bo ^ 65536u);
        HALF(sw0);
        HALF(sw1);
        VMWAIT0();
        __builtin_amdgcn_s_barrier();
        cur ^= 1;
    }
#undef HALF
#undef MF
#undef DSR2
#undef STAGE

    const int er = (lane >> 4) * 4;
#pragma unroll
    for (int i = 0; i < 8; ++i)
#pragma unroll
        for (int j = 0; j < 4; ++j)
#pragma unroll
            for (int rr = 0; rr < 4; ++rr) {
                size_t idx = (size_t)(row0 + wm * 128 + i * 16 + er + rr) * (size_t)ldC +
                             (size_t)(col0 + wn * 64 + j * 16 + fr);
                C[idx] = (OutT)(acc[i][j][rr] * alpha);
            }
}

// ---------------------------------------------------------------------------
__global__ __launch_bounds__(256) void reduce_split2(const float* __restrict__ p,
                                                     float* __restrict__ o, int n4) {
    int i = blockIdx.x * 256 + threadIdx.x;
    if (i >= n4) return;
    const int b  = i >> 18;
    const int jj = i & 262143;
    const float4* p4 = (const float4*)p;
    const size_t base = (size_t)b * 524288 + jj;
    float4 a = p4[base], c = p4[base + 262144];
    float4 s;
    s.x = a.x + c.x;
    s.y = a.y + c.y;
    s.z = a.z + c.z;
    s.w = a.w + c.w;
    ((float4*)o)[i] = s;
}

// ---------------------------------------------------------------------------
__global__ __launch_bounds__(256) void softmax_rows(f16* __restrict__ P) {
    const size_t row = blockIdx.x;
    f16* p = P + row * 1024;
    const int tid = threadIdx.x, lane = tid & 63, wid = tid >> 6;

    f16x4 v4 = *(const f16x4*)(p + tid * 4);
    float v[4];
#pragma unroll
    for (int t = 0; t < 4; ++t) {
        v[t] = (float)v4[t];
        if (v[t] == 0.0f) v[t] = -9e15f;
    }
    float m = fmaxf(fmaxf(v[0], v[1]), fmaxf(v[2], v[3]));
#pragma unroll
    for (int o = 32; o > 0; o >>= 1) m = fmaxf(m, __shfl_xor(m, o));
    __shared__ float red[8];
    if (lane == 0) red[wid] = m;
    __syncthreads();
    m = fmaxf(fmaxf(red[0], red[1]), fmaxf(red[2], red[3]));

    float e[4], s = 0.f;
#pragma unroll
    for (int t = 0; t < 4; ++t) { e[t] = __expf(v[t] - m); s += e[t]; }
#pragma unroll
    for (int o = 32; o > 0; o >>= 1) s += __shfl_xor(s, o);
    if (lane == 0) red[4 + wid] = s;
    __syncthreads();
    s = red[4] + red[5] + red[6] + red[7];
    float inv = 1.0f / s;

    f16x4 o4;
#pragma unroll
    for (int t = 0; t < 4; ++t) o4[t] = (f16)(e[t] * inv);
    *(f16x4*)(p + tid * 4) = o4;
}

// ---------------------------------------------------------------------------
// Algebra (see R6): Mt/G precomputed weight products; Aq=q*Mt^T; P=Aq*k^T;
// Xt=G*v^T; out=P*Xt^T (K=8192, split2). 309 GF. Workspace peak 184 MiB.
extern "C" void kernel_launch(void* const* d_in, const int* in_sizes, int n_in,
                              void* d_out, int out_size, void* d_ws, size_t ws_size,
                              hipStream_t stream) {
    const float* q  = (const float*)d_in[0];
    const float* k  = (const float*)d_in[1];
    const float* v  = (const float*)d_in[2];
    const float* Wq = (const float*)d_in[3];
    const float* Wk = (const float*)d_in[4];
    const float* Wv = (const float*)d_in[5];
    const float* Wl = (const float*)d_in[6];
    float* out = (float*)d_out;

    (void)hipFuncSetAttribute((const void*)gemm2ph<f16>,
                              hipFuncAttributeMaxDynamicSharedMemorySize, 131072);

    const size_t MB = 1024ull * 1024ull;
    char* ws = (char*)d_ws;
    f16*  q_h  = (f16*)(ws + 0 * MB);     // 8 MiB  (dead after Aq)
    f16*  k_h  = (f16*)(ws + 8 * MB);     // 8 MiB  (dead after P)
    f16*  v_h  = (f16*)(ws + 16 * MB);    // 8 MiB  (dead after Xt)
    f16*  Wl_h = (f16*)(ws + 24 * MB);    // 16 MiB (dead after G)
    f16*  WqT  = (f16*)(ws + 40 * MB);    // 16 MiB (dead after Mt)
    f16*  WkT  = (f16*)(ws + 56 * MB);    // 16 MiB (dead after Mt)
    f16*  WvT  = (f16*)(ws + 72 * MB);    // 16 MiB (dead after G)
    f16*  Mt   = (f16*)(ws + 88 * MB);    // 16 MiB (dead after Aq)
    f16*  G    = (f16*)(ws + 104 * MB);   // 16 MiB (dead after Xt)
    f16*  Aq   = (f16*)(ws + 24 * MB);    // 64 MiB over W bufs (dead after P)
    f16*  P    = (f16*)(ws + 120 * MB);   // 64 MiB
    f16*  Xt   = (f16*)(ws + 24 * MB);    // 64 MiB over dead Aq
    float* part = (float*)(ws + 88 * MB); // 32 MiB over dead Mt,G

    Cvt4 c4;
    c4.s[0] = q;  c4.d[0] = q_h;  c4.n8[0] = 524288;
    c4.s[1] = k;  c4.d[1] = k_h;  c4.n8[1] = 524288;
    c4.s[2] = v;  c4.d[2] = v_h;  c4.n8[2] = 524288;
    c4.s[3] = Wl; c4.d[3] = Wl_h; c4.n8[3] = 1048576;
    cvt_plain4<<<dim3(4096, 4), 256, 0, stream>>>(c4);

    T3 t3;
    t3.s[0] = Wq; t3.d[0] = WqT;
    t3.s[1] = Wk; t3.d[1] = WkT;
    t3.s[2] = Wv; t3.d[2] = WvT;
    cvt_transpose3<<<6144, 256, 0, stream>>>(t3);

    const long long M1 = 1048576ll;
    const long long M8 = 8388608ll;
    const float SCALE = 0.03125f;
    dim3 blk(256);
    const size_t SMEM = 131072;

    // ---- Mt_h = BT(WkT_h, WqT_h)  (128^2 engine, K=1024, 512 blocks)
    gemm_bt<f16><<<dim3(8, 8, 8), blk, 0, stream>>>(
        WkT, WqT, Mt, 1024, 1024, 1024, 1024, 1.0f,
        M1, 0, M1, 0, M1, 0, 1);
    // ---- G_h = BT(Wl_h(+h*1024), WvT_h)
    gemm_bt<f16><<<dim3(8, 8, 8), blk, 0, stream>>>(
        Wl_h, WvT, G, 8192, 1024, 1024, 1024, 1.0f,
        1024, 0, M1, 0, M1, 0, 1);
    // ---- Aq[h][b] = BT(q_b, Mt_h)  (256^2 2-phase engine, grid 512)
    gemm2ph<f16><<<512, 512, SMEM, stream>>>(
        q_h, Mt, Aq, 1024, 1024, 1024, 1024, 1.0f,
        0, M1, M1, 0, 4 * M1, M1, 4, 4, 4);
    // ---- P[b][s][h*1024+t] = SCALE * BT(Aq[h][b], k_b)
    gemm2ph<f16><<<512, 512, SMEM, stream>>>(
        Aq, k_h, P, 1024, 1024, 8192, 1024, SCALE,
        4 * M1, M1, 0, M1, 1024, M8, 4, 4, 4);
    // ---- Xt[b][e][h*1024+t] = BT(G_h, v_b)  (overwrites dead Aq)
    gemm2ph<f16><<<512, 512, SMEM, stream>>>(
        G, v_h, Xt, 1024, 1024, 8192, 1024, 1.0f,
        M1, 0, 0, M1, 1024, M8, 4, 4, 4);
    // ---- softmax over 32768 contiguous rows of 1024
    softmax_rows<<<32768, 256, 0, stream>>>(P);
    // ---- out partials: split-K=2, z=(b,ks), K=4096 each (128^2 engine)
    gemm_bt<float><<<dim3(8, 8, 8), blk, 0, stream>>>(
        P, Xt, part, 8192, 8192, 1024, 4096, 1.0f,
        M8, 4096, M8, 4096, 2 * M1, M1, 2);
    reduce_split2<<<4096, 256, 0, stream>>>(part, out, 1048576);
}